// Round 3
// baseline (246.537 us; speedup 1.0000x reference)
//
#include <hip/hip_runtime.h>
#include <hip/hip_bf16.h>

#define B_   4
#define S_   8192
#define D_   512
#define DFF_ 2048
#define K_TOP 1024
#define KS1  16      // D_/32
#define KS2  64      // DFF_/32

typedef unsigned short u16;
typedef __attribute__((ext_vector_type(8))) short bf16x8;
typedef __attribute__((ext_vector_type(4))) float floatx4;

// monotonic float -> uint key (order-preserving)
__device__ __forceinline__ unsigned f2key(float f){
    unsigned u = __float_as_uint(f);
    return (u & 0x80000000u) ? ~u : (u | 0x80000000u);
}
// fp32 -> bf16 round-to-nearest-even
__device__ __forceinline__ u16 f2b(float f){
    unsigned u = __float_as_uint(f);
    u = (u + 0x7FFFu + ((u >> 16) & 1u)) >> 16;
    return (u16)u;
}
__device__ __forceinline__ float gelu_tanh(float v){
    float c = 0.7978845608028654f * (v + 0.044715f * v * v * v);
    return 0.5f * v * (1.0f + tanhf(c));
}
// async global->LDS, 16B per lane (wave-uniform base + lane*16)
__device__ __forceinline__ void gl_lds16(const void* gptr, void* lptr){
    auto g = (const __attribute__((address_space(1))) unsigned int*)((uintptr_t)gptr);
    auto l = (__attribute__((address_space(3))) unsigned int*)((uintptr_t)lptr);
    __builtin_amdgcn_global_load_lds(g, l, 16, 0, 0);
}

// ---------------- kernel 1: router weights + x -> out passthrough ----------
__global__ __launch_bounds__(256) void wts_copy_kernel(
    const float4* __restrict__ x, float4* __restrict__ out,
    const float4* __restrict__ Wr4, const float* __restrict__ br,
    float* __restrict__ w_all, int* __restrict__ count)
{
    if (blockIdx.x == 0 && threadIdx.x == 0) *count = 0;
    const int wv = threadIdx.x >> 6, lane = threadIdx.x & 63;
    const int token = blockIdx.x * 4 + wv;
    const float4* xt = x + (size_t)token * 128;
    float acc = 0.f;
    #pragma unroll
    for (int i = 0; i < 2; i++){
        int j = lane + i * 64;
        float4 v = xt[j];
        out[(size_t)token * 128 + j] = v;
        float4 wvv = Wr4[j];
        acc += v.x*wvv.x + v.y*wvv.y + v.z*wvv.z + v.w*wvv.w;
    }
    #pragma unroll
    for (int off = 32; off > 0; off >>= 1) acc += __shfl_down(acc, off, 64);
    if (lane == 0) w_all[token] = acc + br[0];
}

// ------- kernel 2: exact k-th largest per batch (LDS radix select) + compact
__global__ __launch_bounds__(1024) void kth_compact_kernel(
    const float4* __restrict__ w_all4, int* __restrict__ count,
    int* __restrict__ idx)
{
    __shared__ unsigned keys[S_];
    __shared__ unsigned hist[16][256];
    __shared__ unsigned suffix[256];
    __shared__ unsigned sprefix;
    __shared__ int sremk;
    const int b = blockIdx.x, tid = threadIdx.x, wv = tid >> 6;
    const float4* row4 = w_all4 + (size_t)b * (S_ / 4);

    #pragma unroll
    for (int i = 0; i < 2; i++){
        int j = tid + i * 1024;
        float4 v = row4[j];
        keys[4*j+0] = f2key(v.x); keys[4*j+1] = f2key(v.y);
        keys[4*j+2] = f2key(v.z); keys[4*j+3] = f2key(v.w);
    }
    if (tid == 0){ sprefix = 0u; sremk = K_TOP; }
    __syncthreads();

    for (int pass = 3; pass >= 0; pass--){
        for (int i = tid; i < 16 * 256; i += 1024) ((unsigned*)hist)[i] = 0u;
        __syncthreads();
        const unsigned mask_hi = (pass == 3) ? 0u : (0xFFFFFFFFu << ((pass + 1) * 8));
        const unsigned pfx = sprefix;
        const int shift = pass * 8;
        #pragma unroll
        for (int i = 0; i < 8; i++){
            unsigned key = keys[tid + i * 1024];
            if ((key & mask_hi) == pfx)
                atomicAdd(&hist[wv][(key >> shift) & 255u], 1u);
        }
        __syncthreads();
        if (tid < 256){
            unsigned s = 0;
            #pragma unroll
            for (int h = 0; h < 16; h++) s += hist[h][tid];
            suffix[tid] = s;
        }
        __syncthreads();
        for (int off = 1; off < 256; off <<= 1){
            unsigned v = 0;
            if (tid < 256 && tid + off < 256) v = suffix[tid + off];
            __syncthreads();
            if (tid < 256) suffix[tid] += v;
            __syncthreads();
        }
        const int remk = sremk;
        __syncthreads();
        if (tid < 256){
            unsigned snext = (tid == 255) ? 0u : suffix[tid + 1];
            if (suffix[tid] >= (unsigned)remk && snext < (unsigned)remk){
                sprefix = pfx | ((unsigned)tid << shift);
                sremk = remk - (int)snext;
            }
        }
        __syncthreads();
    }

    const unsigned thr = sprefix;
    #pragma unroll
    for (int i = 0; i < 8; i++){
        int li = tid + i * 1024;
        if (keys[li] > thr){
            int p = atomicAdd(count, 1);
            idx[p] = b * S_ + li;
        }
    }
}

// --- kernel 3: gather selected x rows -> bf16, tiled [mt][ks][128][32] -----
__global__ __launch_bounds__(256) void gather_kernel(
    const float* __restrict__ x, const int* __restrict__ idx,
    const int* __restrict__ countp, u16* __restrict__ XbT)
{
    const int mt = blockIdx.x;                 // 0..31
    const int w = threadIdx.x >> 6, lane = threadIdx.x & 63;
    const int cnt = *countp;
    const int ks = lane >> 2, c8 = (lane & 3) * 8;
    for (int rr = 0; rr < 32; rr++){
        int r = w * 32 + rr;
        int mg = mt * 128 + r;
        float4 v0 = {0,0,0,0}, v1 = {0,0,0,0};
        if (mg < cnt){
            const float* xp = x + (size_t)idx[mg] * D_ + lane * 8;
            v0 = *(const float4*)xp; v1 = *(const float4*)(xp + 4);
        }
        bf16x8 bv;
        bv[0]=(short)f2b(v0.x); bv[1]=(short)f2b(v0.y);
        bv[2]=(short)f2b(v0.z); bv[3]=(short)f2b(v0.w);
        bv[4]=(short)f2b(v1.x); bv[5]=(short)f2b(v1.y);
        bv[6]=(short)f2b(v1.z); bv[7]=(short)f2b(v1.w);
        *(bf16x8*)&XbT[((size_t)(mt * KS1 + ks) * 128 + r) * 32 + c8] = bv;
    }
}

// --- kernel 4: weight fp32 [R][C] -> bf16 tiled [C/128][R/32][128][32] -----
__global__ __launch_bounds__(256) void tconv_kernel(
    const float* __restrict__ src, u16* __restrict__ dst, int R, int C)
{
    __shared__ float tile[32][132];
    const int nt = blockIdx.x, ks = blockIdx.y;
    const int n0 = nt * 128, k0 = ks * 32;
    const int tid = threadIdx.x;
    #pragma unroll
    for (int i = 0; i < 16; i++){
        int lin = tid + i * 256;
        int kk = lin >> 7, nn = lin & 127;
        tile[kk][nn] = src[(size_t)(k0 + kk) * C + n0 + nn];
    }
    __syncthreads();
    size_t base = ((size_t)(nt * (R / 32) + ks)) * 4096;
    #pragma unroll
    for (int i = 0; i < 2; i++){
        int chunk = tid + i * 256;
        int r = chunk >> 2, c8 = (chunk & 3) * 8;
        bf16x8 bv;
        #pragma unroll
        for (int e = 0; e < 8; e++) bv[e] = (short)f2b(tile[c8 + e][r]);
        *(bf16x8*)&dst[base + r * 32 + c8] = bv;
    }
}

// --- kernel 5: GEMM1  Ht = gelu(Xsel @ W1 + b1), 128x128 tile, gl_lds ------
__global__ __launch_bounds__(256) void ffn1_kernel(
    const u16* __restrict__ XbT, const u16* __restrict__ W1t,
    const int* __restrict__ countp, const float* __restrict__ bias1,
    u16* __restrict__ Ht)
{
    __shared__ __align__(16) u16 As[128 * 32];
    __shared__ __align__(16) u16 Bs[128 * 32];
    const int tid = threadIdx.x;
    const int cnt = *countp;
    const int mBlk = blockIdx.x, nBlk = blockIdx.y;
    const int lane = tid & 63, w = tid >> 6;
    const int wr = (w >> 1) * 64, wc = (w & 1) * 64;
    const int fr = lane & 15, quad = lane >> 4, kq8 = quad * 8;

    const char* Ag = (const char*)(XbT + (size_t)mBlk * KS1 * 4096) + tid * 16;
    const char* Bg = (const char*)(W1t + (size_t)nBlk * KS1 * 4096) + tid * 16;
    char* Al = (char*)As + tid * 16;
    char* Bl = (char*)Bs + tid * 16;

    floatx4 acc[4][4] = {};
    for (int ksi = 0; ksi < KS1; ksi++){
        gl_lds16(Ag, Al); gl_lds16(Ag + 4096, Al + 4096);
        gl_lds16(Bg, Bl); gl_lds16(Bg + 4096, Bl + 4096);
        Ag += 8192; Bg += 8192;
        __syncthreads();
        bf16x8 af[4], bf[4];
        #pragma unroll
        for (int i = 0; i < 4; i++) af[i] = *(const bf16x8*)&As[(wr + i*16 + fr) * 32 + kq8];
        #pragma unroll
        for (int j = 0; j < 4; j++) bf[j] = *(const bf16x8*)&Bs[(wc + j*16 + fr) * 32 + kq8];
        #pragma unroll
        for (int i = 0; i < 4; i++)
            #pragma unroll
            for (int j = 0; j < 4; j++)
                acc[i][j] = __builtin_amdgcn_mfma_f32_16x16x32_bf16(af[i], bf[j], acc[i][j], 0, 0, 0);
        __syncthreads();
    }

    float bj[4];
    #pragma unroll
    for (int j = 0; j < 4; j++) bj[j] = bias1[nBlk*128 + wc + j*16 + fr];
    const int rbase = quad * 4;
    #pragma unroll
    for (int i = 0; i < 4; i++){
        int r128b = wr + i*16 + rbase;
        #pragma unroll
        for (int rg = 0; rg < 4; rg++){
            int r128 = r128b + rg;
            int mg = mBlk*128 + r128;
            if (mg < cnt){
                #pragma unroll
                for (int j = 0; j < 4; j++){
                    int n = nBlk*128 + wc + j*16 + fr;
                    float v = gelu_tanh(acc[i][j][rg] + bj[j]);
                    Ht[((size_t)(mBlk * KS2 + (n >> 5)) * 128 + r128) * 32 + (n & 31)] = f2b(v);
                }
            }
        }
    }
}

// --- kernel 6: GEMM2  out[token] = (H @ W2 + b2) * w, scatter --------------
__global__ __launch_bounds__(256) void ffn2_kernel(
    const u16* __restrict__ Ht, const u16* __restrict__ W2t,
    const int* __restrict__ countp, const int* __restrict__ idx,
    const float* __restrict__ w_all, const float* __restrict__ bias2,
    float* __restrict__ out)
{
    __shared__ __align__(16) u16 As[128 * 32];
    __shared__ __align__(16) u16 Bs[128 * 32];
    const int tid = threadIdx.x;
    const int cnt = *countp;
    const int mBlk = blockIdx.x, nBlk = blockIdx.y;
    const int lane = tid & 63, w = tid >> 6;
    const int wr = (w >> 1) * 64, wc = (w & 1) * 64;
    const int fr = lane & 15, quad = lane >> 4, kq8 = quad * 8;

    const char* Ag = (const char*)(Ht + (size_t)mBlk * KS2 * 4096) + tid * 16;
    const char* Bg = (const char*)(W2t + (size_t)nBlk * KS2 * 4096) + tid * 16;
    char* Al = (char*)As + tid * 16;
    char* Bl = (char*)Bs + tid * 16;

    floatx4 acc[4][4] = {};
    for (int ksi = 0; ksi < KS2; ksi++){
        gl_lds16(Ag, Al); gl_lds16(Ag + 4096, Al + 4096);
        gl_lds16(Bg, Bl); gl_lds16(Bg + 4096, Bl + 4096);
        Ag += 8192; Bg += 8192;
        __syncthreads();
        bf16x8 af[4], bf[4];
        #pragma unroll
        for (int i = 0; i < 4; i++) af[i] = *(const bf16x8*)&As[(wr + i*16 + fr) * 32 + kq8];
        #pragma unroll
        for (int j = 0; j < 4; j++) bf[j] = *(const bf16x8*)&Bs[(wc + j*16 + fr) * 32 + kq8];
        #pragma unroll
        for (int i = 0; i < 4; i++)
            #pragma unroll
            for (int j = 0; j < 4; j++)
                acc[i][j] = __builtin_amdgcn_mfma_f32_16x16x32_bf16(af[i], bf[j], acc[i][j], 0, 0, 0);
        __syncthreads();
    }

    float bj[4];
    #pragma unroll
    for (int j = 0; j < 4; j++) bj[j] = bias2[nBlk*128 + wc + j*16 + fr];
    const int rbase = quad * 4;
    #pragma unroll
    for (int i = 0; i < 4; i++){
        #pragma unroll
        for (int rg = 0; rg < 4; rg++){
            int mg = mBlk*128 + wr + i*16 + rbase + rg;
            if (mg < cnt){
                int token = idx[mg];
                float wt = w_all[token];
                float* op = out + (size_t)token * D_;
                #pragma unroll
                for (int j = 0; j < 4; j++){
                    int n = nBlk*128 + wc + j*16 + fr;
                    op[n] = (acc[i][j][rg] + bj[j]) * wt;
                }
            }
        }
    }
}

extern "C" void kernel_launch(void* const* d_in, const int* in_sizes, int n_in,
                              void* d_out, int out_size, void* d_ws, size_t ws_size,
                              hipStream_t stream)
{
    const float* x  = (const float*)d_in[0];
    const float* Wr = (const float*)d_in[2];
    const float* br = (const float*)d_in[3];
    const float* W1 = (const float*)d_in[4];
    const float* b1 = (const float*)d_in[5];
    const float* W2 = (const float*)d_in[6];
    const float* b2 = (const float*)d_in[7];
    float* out = (float*)d_out;
    char* ws = (char*)d_ws;

    // workspace layout (bytes)
    float* w_all = (float*)(ws + 0);          // 32768 f32 (128 KB)
    int*   count = (int*)  (ws + 131088);
    int*   idx   = (int*)  (ws + 131104);     // 4096 ints
    u16*   XbT   = (u16*)  (ws + 262144);     // 4 MB  tiled [32][16][128][32]
    u16*   W1t   = (u16*)  (ws + 4456448);    // 2 MB  tiled [16][16][128][32]
    u16*   W2t   = (u16*)  (ws + 6553600);    // 2 MB  tiled [4][64][128][32]
    u16*   Ht    = (u16*)  (ws + 8650752);    // 16 MB tiled [32][64][128][32]

    tconv_kernel<<<dim3(DFF_/128, D_/32),  256, 0, stream>>>(W1, W1t, D_, DFF_);
    tconv_kernel<<<dim3(D_/128,  DFF_/32), 256, 0, stream>>>(W2, W2t, DFF_, D_);
    wts_copy_kernel<<<(B_*S_)/4, 256, 0, stream>>>(
        (const float4*)x, (float4*)out, (const float4*)Wr, br, w_all, count);
    kth_compact_kernel<<<B_, 1024, 0, stream>>>((const float4*)w_all, count, idx);
    gather_kernel<<<32, 256, 0, stream>>>(x, idx, count, XbT);
    ffn1_kernel<<<dim3(32, DFF_/128), 256, 0, stream>>>(XbT, W1t, count, b1, Ht);
    ffn2_kernel<<<dim3(32, D_/128),   256, 0, stream>>>(Ht, W2t, count, idx, w_all, b2, out);
}

// Round 4
// 208.295 us; speedup vs baseline: 1.1836x; 1.1836x over previous
//
#include <hip/hip_runtime.h>
#include <hip/hip_bf16.h>

#define B_   4
#define S_   8192
#define D_   512
#define DFF_ 2048
#define K_TOP 1024
#define KS1  8       // D_/64
#define KS2  32      // DFF_/64
#define TILE_E (128*64)   // elems per [128][64] k-step tile

typedef unsigned short u16;
typedef __attribute__((ext_vector_type(8))) short bf16x8;
typedef __attribute__((ext_vector_type(4))) float floatx4;

// monotonic float -> uint key (order-preserving)
__device__ __forceinline__ unsigned f2key(float f){
    unsigned u = __float_as_uint(f);
    return (u & 0x80000000u) ? ~u : (u | 0x80000000u);
}
// fp32 -> bf16 round-to-nearest-even
__device__ __forceinline__ u16 f2b(float f){
    unsigned u = __float_as_uint(f);
    u = (u + 0x7FFFu + ((u >> 16) & 1u)) >> 16;
    return (u16)u;
}
__device__ __forceinline__ float gelu_tanh(float v){
    float c = 0.7978845608028654f * (v + 0.044715f * v * v * v);
    return 0.5f * v * (1.0f + tanhf(c));
}
// async global->LDS, 16B per lane (wave-uniform base + lane*16)
__device__ __forceinline__ void gl_lds16(const void* gptr, void* lptr){
    auto g = (const __attribute__((address_space(1))) unsigned int*)((uintptr_t)gptr);
    auto l = (__attribute__((address_space(3))) unsigned int*)((uintptr_t)lptr);
    __builtin_amdgcn_global_load_lds(g, l, 16, 0, 0);
}

// Tiled-swizzled operand layout: [tile][kstep][128 rows][64 kcols] bf16,
// 16B chunk c of row r stored at chunk position (c ^ (r&7)).  This makes the
// MFMA fragment ds_read_b128 pattern (16 rows per quad) hit all 32 banks.

// ---------------- kernel 1: router weights + x -> out passthrough ----------
__global__ __launch_bounds__(256) void wts_copy_kernel(
    const float4* __restrict__ x, float4* __restrict__ out,
    const float4* __restrict__ Wr4, const float* __restrict__ br,
    float* __restrict__ w_all, int* __restrict__ count)
{
    if (blockIdx.x == 0 && threadIdx.x == 0) *count = 0;
    const int wv = threadIdx.x >> 6, lane = threadIdx.x & 63;
    const int token = blockIdx.x * 4 + wv;
    const float4* xt = x + (size_t)token * 128;
    float acc = 0.f;
    #pragma unroll
    for (int i = 0; i < 2; i++){
        int j = lane + i * 64;
        float4 v = xt[j];
        out[(size_t)token * 128 + j] = v;
        float4 wvv = Wr4[j];
        acc += v.x*wvv.x + v.y*wvv.y + v.z*wvv.z + v.w*wvv.w;
    }
    #pragma unroll
    for (int off = 32; off > 0; off >>= 1) acc += __shfl_down(acc, off, 64);
    if (lane == 0) w_all[token] = acc + br[0];
}

// ------- kernel 2: exact k-th largest per batch (LDS radix select) + compact
__global__ __launch_bounds__(1024) void kth_compact_kernel(
    const float4* __restrict__ w_all4, int* __restrict__ count,
    int* __restrict__ idx)
{
    __shared__ unsigned keys[S_];
    __shared__ unsigned hist[16][256];
    __shared__ unsigned suffix[256];
    __shared__ unsigned sprefix;
    __shared__ int sremk;
    const int b = blockIdx.x, tid = threadIdx.x, wv = tid >> 6;
    const float4* row4 = w_all4 + (size_t)b * (S_ / 4);

    #pragma unroll
    for (int i = 0; i < 2; i++){
        int j = tid + i * 1024;
        float4 v = row4[j];
        keys[4*j+0] = f2key(v.x); keys[4*j+1] = f2key(v.y);
        keys[4*j+2] = f2key(v.z); keys[4*j+3] = f2key(v.w);
    }
    if (tid == 0){ sprefix = 0u; sremk = K_TOP; }
    __syncthreads();

    for (int pass = 3; pass >= 0; pass--){
        for (int i = tid; i < 16 * 256; i += 1024) ((unsigned*)hist)[i] = 0u;
        __syncthreads();
        const unsigned mask_hi = (pass == 3) ? 0u : (0xFFFFFFFFu << ((pass + 1) * 8));
        const unsigned pfx = sprefix;
        const int shift = pass * 8;
        #pragma unroll
        for (int i = 0; i < 8; i++){
            unsigned key = keys[tid + i * 1024];
            if ((key & mask_hi) == pfx)
                atomicAdd(&hist[wv][(key >> shift) & 255u], 1u);
        }
        __syncthreads();
        if (tid < 256){
            unsigned s = 0;
            #pragma unroll
            for (int h = 0; h < 16; h++) s += hist[h][tid];
            suffix[tid] = s;
        }
        __syncthreads();
        for (int off = 1; off < 256; off <<= 1){
            unsigned v = 0;
            if (tid < 256 && tid + off < 256) v = suffix[tid + off];
            __syncthreads();
            if (tid < 256) suffix[tid] += v;
            __syncthreads();
        }
        const int remk = sremk;
        __syncthreads();
        if (tid < 256){
            unsigned snext = (tid == 255) ? 0u : suffix[tid + 1];
            if (suffix[tid] >= (unsigned)remk && snext < (unsigned)remk){
                sprefix = pfx | ((unsigned)tid << shift);
                sremk = remk - (int)snext;
            }
        }
        __syncthreads();
    }

    const unsigned thr = sprefix;
    #pragma unroll
    for (int i = 0; i < 8; i++){
        int li = tid + i * 1024;
        if (keys[li] > thr){
            int p = atomicAdd(count, 1);
            idx[p] = b * S_ + li;
        }
    }
}

// --- kernel 3: gather selected x rows -> bf16 tiled+swizzled ---------------
// grid (32 m-tiles, 8 k-steps); 8 lanes cover one row's 64-float slice.
__global__ __launch_bounds__(256) void gather_kernel(
    const float* __restrict__ x, const int* __restrict__ idx,
    const int* __restrict__ countp, u16* __restrict__ XbT)
{
    const int mt = blockIdx.x, s = blockIdx.y;
    const int cnt = *countp;
    const int cl = threadIdx.x & 7, rb = threadIdx.x >> 3;   // rb 0..31
    #pragma unroll
    for (int it = 0; it < 4; it++){
        int r = rb + it * 32;
        int mg = mt * 128 + r;
        if (mg < cnt){
            const float* xp = x + (size_t)idx[mg] * D_ + s * 64 + cl * 8;
            float4 v0 = *(const float4*)xp;
            float4 v1 = *(const float4*)(xp + 4);
            bf16x8 bv;
            bv[0]=(short)f2b(v0.x); bv[1]=(short)f2b(v0.y);
            bv[2]=(short)f2b(v0.z); bv[3]=(short)f2b(v0.w);
            bv[4]=(short)f2b(v1.x); bv[5]=(short)f2b(v1.y);
            bv[6]=(short)f2b(v1.z); bv[7]=(short)f2b(v1.w);
            *(bf16x8*)&XbT[((size_t)(mt * KS1 + s) * 128 + r) * 64
                           + ((cl ^ (r & 7)) << 3)] = bv;
        }
    }
}

// --- kernel 4: weight fp32 [R][C] -> bf16 tiled+swizzled -------------------
// dst tiles [C/128][R/64][128][64]; grid (C/128, R/64)
__global__ __launch_bounds__(256) void tconv_kernel(
    const float* __restrict__ src, u16* __restrict__ dst, int R, int C)
{
    __shared__ float tile[64][132];
    const int ct = blockIdx.x, s = blockIdx.y;
    const int tid = threadIdx.x;
    #pragma unroll
    for (int it = 0; it < 32; it++){
        int lin = it * 256 + tid;
        int kk = lin >> 7, nn = lin & 127;
        tile[kk][nn] = src[(size_t)(s * 64 + kk) * C + ct * 128 + nn];
    }
    __syncthreads();
    size_t base = ((size_t)(ct * (R / 64) + s)) * TILE_E;
    #pragma unroll
    for (int it = 0; it < 4; it++){
        int task = it * 256 + tid;
        int r = task >> 3, cl = task & 7;
        bf16x8 bv;
        #pragma unroll
        for (int e = 0; e < 8; e++) bv[e] = (short)f2b(tile[cl * 8 + e][r]);
        *(bf16x8*)&dst[base + (size_t)r * 64 + ((cl ^ (r & 7)) << 3)] = bv;
    }
}

// --- kernel 5: GEMM1  Ht = gelu(Xsel @ W1 + b1), BK=64, dbuf, 1 barrier ----
__global__ __launch_bounds__(256) void ffn1_kernel(
    const u16* __restrict__ XbT, const u16* __restrict__ W1t,
    const int* __restrict__ countp, const float* __restrict__ bias1,
    u16* __restrict__ Ht)
{
    __shared__ __align__(16) u16 As[2][TILE_E];
    __shared__ __align__(16) u16 Bs[2][TILE_E];
    const int tid = threadIdx.x;
    const int cnt = *countp;
    const int mBlk = blockIdx.x, nBlk = blockIdx.y;
    const int lane = tid & 63, w = tid >> 6;
    const int wr = (w >> 1) * 64, wc = (w & 1) * 64;
    const int fr = lane & 15, quad = lane >> 4, fx = fr & 7;

    const char* Ag = (const char*)(XbT + (size_t)mBlk * KS1 * TILE_E) + tid * 16;
    const char* Bg = (const char*)(W1t + (size_t)nBlk * KS1 * TILE_E) + tid * 16;

    // prologue: stage step 0 into buffer 0
    #pragma unroll
    for (int i = 0; i < 4; i++){
        gl_lds16(Ag + i*4096, (char*)As[0] + tid*16 + i*4096);
        gl_lds16(Bg + i*4096, (char*)Bs[0] + tid*16 + i*4096);
    }

    floatx4 acc[4][4] = {};
    for (int ksi = 0; ksi < KS1; ksi++){
        __syncthreads();                       // drains loads for buf[ksi&1]
        if (ksi + 1 < KS1){
            const char* An = Ag + (size_t)(ksi+1) * 16384;
            const char* Bn = Bg + (size_t)(ksi+1) * 16384;
            char* Al = (char*)As[(ksi+1)&1] + tid*16;
            char* Bl = (char*)Bs[(ksi+1)&1] + tid*16;
            #pragma unroll
            for (int i = 0; i < 4; i++){
                gl_lds16(An + i*4096, Al + i*4096);
                gl_lds16(Bn + i*4096, Bl + i*4096);
            }
        }
        const u16* Ab = As[ksi&1];
        const u16* Bb = Bs[ksi&1];
        #pragma unroll
        for (int sub = 0; sub < 2; sub++){
            const int cch = ((sub*4 + quad) ^ fx) << 3;
            bf16x8 af[4], bf[4];
            #pragma unroll
            for (int i = 0; i < 4; i++) af[i] = *(const bf16x8*)&Ab[(wr + i*16 + fr)*64 + cch];
            #pragma unroll
            for (int j = 0; j < 4; j++) bf[j] = *(const bf16x8*)&Bb[(wc + j*16 + fr)*64 + cch];
            #pragma unroll
            for (int i = 0; i < 4; i++)
                #pragma unroll
                for (int j = 0; j < 4; j++)
                    acc[i][j] = __builtin_amdgcn_mfma_f32_16x16x32_bf16(af[i], bf[j], acc[i][j], 0, 0, 0);
        }
    }

    float bj[4];
    #pragma unroll
    for (int j = 0; j < 4; j++) bj[j] = bias1[nBlk*128 + wc + j*16 + fr];
    const int rbase = quad * 4;
    #pragma unroll
    for (int i = 0; i < 4; i++){
        #pragma unroll
        for (int rg = 0; rg < 4; rg++){
            int r128 = wr + i*16 + rbase + rg;
            int mg = mBlk*128 + r128;
            if (mg < cnt){
                #pragma unroll
                for (int j = 0; j < 4; j++){
                    int n = nBlk*128 + wc + j*16 + fr;
                    float v = gelu_tanh(acc[i][j][rg] + bj[j]);
                    // Ht in ffn2's A layout: tile mBlk, kstep n>>6, row r128, kcol n&63
                    Ht[((size_t)(mBlk * KS2 + (n >> 6)) * 128 + r128) * 64
                       + ((((n >> 3) & 7) ^ (r128 & 7)) << 3) + (n & 7)] = f2b(v);
                }
            }
        }
    }
}

// --- kernel 6: GEMM2  out[token] = (H @ W2 + b2) * w, BK=64, dbuf ----------
__global__ __launch_bounds__(256) void ffn2_kernel(
    const u16* __restrict__ Ht, const u16* __restrict__ W2t,
    const int* __restrict__ countp, const int* __restrict__ idx,
    const float* __restrict__ w_all, const float* __restrict__ bias2,
    float* __restrict__ out)
{
    __shared__ __align__(16) u16 As[2][TILE_E];
    __shared__ __align__(16) u16 Bs[2][TILE_E];
    const int tid = threadIdx.x;
    const int cnt = *countp;
    const int mBlk = blockIdx.x, nBlk = blockIdx.y;
    const int lane = tid & 63, w = tid >> 6;
    const int wr = (w >> 1) * 64, wc = (w & 1) * 64;
    const int fr = lane & 15, quad = lane >> 4, fx = fr & 7;

    const char* Ag = (const char*)(Ht + (size_t)mBlk * KS2 * TILE_E) + tid * 16;
    const char* Bg = (const char*)(W2t + (size_t)nBlk * KS2 * TILE_E) + tid * 16;

    #pragma unroll
    for (int i = 0; i < 4; i++){
        gl_lds16(Ag + i*4096, (char*)As[0] + tid*16 + i*4096);
        gl_lds16(Bg + i*4096, (char*)Bs[0] + tid*16 + i*4096);
    }

    floatx4 acc[4][4] = {};
    for (int ksi = 0; ksi < KS2; ksi++){
        __syncthreads();
        if (ksi + 1 < KS2){
            const char* An = Ag + (size_t)(ksi+1) * 16384;
            const char* Bn = Bg + (size_t)(ksi+1) * 16384;
            char* Al = (char*)As[(ksi+1)&1] + tid*16;
            char* Bl = (char*)Bs[(ksi+1)&1] + tid*16;
            #pragma unroll
            for (int i = 0; i < 4; i++){
                gl_lds16(An + i*4096, Al + i*4096);
                gl_lds16(Bn + i*4096, Bl + i*4096);
            }
        }
        const u16* Ab = As[ksi&1];
        const u16* Bb = Bs[ksi&1];
        #pragma unroll
        for (int sub = 0; sub < 2; sub++){
            const int cch = ((sub*4 + quad) ^ fx) << 3;
            bf16x8 af[4], bf[4];
            #pragma unroll
            for (int i = 0; i < 4; i++) af[i] = *(const bf16x8*)&Ab[(wr + i*16 + fr)*64 + cch];
            #pragma unroll
            for (int j = 0; j < 4; j++) bf[j] = *(const bf16x8*)&Bb[(wc + j*16 + fr)*64 + cch];
            #pragma unroll
            for (int i = 0; i < 4; i++)
                #pragma unroll
                for (int j = 0; j < 4; j++)
                    acc[i][j] = __builtin_amdgcn_mfma_f32_16x16x32_bf16(af[i], bf[j], acc[i][j], 0, 0, 0);
        }
    }

    float bj[4];
    #pragma unroll
    for (int j = 0; j < 4; j++) bj[j] = bias2[nBlk*128 + wc + j*16 + fr];
    const int rbase = quad * 4;
    #pragma unroll
    for (int i = 0; i < 4; i++){
        #pragma unroll
        for (int rg = 0; rg < 4; rg++){
            int mg = mBlk*128 + wr + i*16 + rbase + rg;
            if (mg < cnt){
                int token = idx[mg];
                float wt = w_all[token];
                float* op = out + (size_t)token * D_;
                #pragma unroll
                for (int j = 0; j < 4; j++){
                    int n = nBlk*128 + wc + j*16 + fr;
                    op[n] = (acc[i][j][rg] + bj[j]) * wt;
                }
            }
        }
    }
}

extern "C" void kernel_launch(void* const* d_in, const int* in_sizes, int n_in,
                              void* d_out, int out_size, void* d_ws, size_t ws_size,
                              hipStream_t stream)
{
    const float* x  = (const float*)d_in[0];
    const float* Wr = (const float*)d_in[2];
    const float* br = (const float*)d_in[3];
    const float* W1 = (const float*)d_in[4];
    const float* b1 = (const float*)d_in[5];
    const float* W2 = (const float*)d_in[6];
    const float* b2 = (const float*)d_in[7];
    float* out = (float*)d_out;
    char* ws = (char*)d_ws;

    // workspace layout (bytes)
    float* w_all = (float*)(ws + 0);          // 128 KB
    int*   count = (int*)  (ws + 131088);
    int*   idx   = (int*)  (ws + 131104);     // 4096 ints
    u16*   XbT   = (u16*)  (ws + 262144);     // 4 MB  [32][8][128][64]
    u16*   W1t   = (u16*)  (ws + 4456448);    // 2 MB  [16][8][128][64]
    u16*   W2t   = (u16*)  (ws + 6553600);    // 2 MB  [4][32][128][64]
    u16*   Ht    = (u16*)  (ws + 8650752);    // 16 MB [32][32][128][64]

    tconv_kernel<<<dim3(DFF_/128, D_/64),  256, 0, stream>>>(W1, W1t, D_, DFF_);
    tconv_kernel<<<dim3(D_/128,  DFF_/64), 256, 0, stream>>>(W2, W2t, DFF_, D_);
    wts_copy_kernel<<<(B_*S_)/4, 256, 0, stream>>>(
        (const float4*)x, (float4*)out, (const float4*)Wr, br, w_all, count);
    kth_compact_kernel<<<B_, 1024, 0, stream>>>((const float4*)w_all, count, idx);
    gather_kernel<<<dim3(32, KS1), 256, 0, stream>>>(x, idx, count, XbT);
    ffn1_kernel<<<dim3(32, DFF_/128), 256, 0, stream>>>(XbT, W1t, count, b1, Ht);
    ffn2_kernel<<<dim3(32, D_/128),   256, 0, stream>>>(Ht, W2t, count, idx, w_all, b2, out);
}

// Round 5
// 206.038 us; speedup vs baseline: 1.1966x; 1.0110x over previous
//
#include <hip/hip_runtime.h>
#include <hip/hip_bf16.h>

#define B_   4
#define S_   8192
#define D_   512
#define DFF_ 2048
#define K_TOP 1024

typedef unsigned short u16;
typedef __attribute__((ext_vector_type(8))) short bf16x8;
typedef __attribute__((ext_vector_type(4))) float floatx4;

// monotonic float -> uint key (order-preserving)
__device__ __forceinline__ unsigned f2key(float f){
    unsigned u = __float_as_uint(f);
    return (u & 0x80000000u) ? ~u : (u | 0x80000000u);
}
// fp32 -> bf16 round-to-nearest-even
__device__ __forceinline__ u16 f2b(float f){
    unsigned u = __float_as_uint(f);
    u = (u + 0x7FFFu + ((u >> 16) & 1u)) >> 16;
    return (u16)u;
}
// fast tanh-gelu via v_exp_f32: gelu = v - v/(exp(2c)+1), 2c = 1.59576912(v + 0.044715 v^3)
__device__ __forceinline__ float gelu_fast(float v){
    float u = 1.5957691216f * v + 0.0713548162726f * v * v * v;
    float e = __expf(u);
    return v - v / (e + 1.0f);
}
// async global->LDS, 16B per lane (wave-uniform base + lane*16)
__device__ __forceinline__ void gl_lds16(const void* gptr, void* lptr){
    auto g = (const __attribute__((address_space(1))) unsigned int*)((uintptr_t)gptr);
    auto l = (__attribute__((address_space(3))) unsigned int*)((uintptr_t)lptr);
    __builtin_amdgcn_global_load_lds(g, l, 16, 0, 0);
}

// All GEMM operand tiles: [tile][kstep][rows][128 kcols] bf16, 16B chunk c of
// row r stored at chunk position (c ^ (r&15)) -> conflict-free ds_read_b128.

// ---------------- kernel 1: router weights + x -> out passthrough ----------
__global__ __launch_bounds__(256) void wts_copy_kernel(
    const float4* __restrict__ x, float4* __restrict__ out,
    const float4* __restrict__ Wr4, const float* __restrict__ br,
    float* __restrict__ w_all, int* __restrict__ count)
{
    if (blockIdx.x == 0 && threadIdx.x == 0) *count = 0;
    const int wv = threadIdx.x >> 6, lane = threadIdx.x & 63;
    const int token = blockIdx.x * 4 + wv;
    const float4* xt = x + (size_t)token * 128;
    float acc = 0.f;
    #pragma unroll
    for (int i = 0; i < 2; i++){
        int j = lane + i * 64;
        float4 v = xt[j];
        out[(size_t)token * 128 + j] = v;
        float4 wvv = Wr4[j];
        acc += v.x*wvv.x + v.y*wvv.y + v.z*wvv.z + v.w*wvv.w;
    }
    #pragma unroll
    for (int off = 32; off > 0; off >>= 1) acc += __shfl_down(acc, off, 64);
    if (lane == 0) w_all[token] = acc + br[0];
}

// ------- kernel 2: exact k-th largest per batch (LDS radix select) + compact
__global__ __launch_bounds__(1024) void kth_compact_kernel(
    const float4* __restrict__ w_all4, int* __restrict__ count,
    int* __restrict__ idx)
{
    __shared__ unsigned keys[S_];
    __shared__ unsigned hist[16][256];
    __shared__ unsigned suffix[256];
    __shared__ unsigned sprefix;
    __shared__ int sremk;
    const int b = blockIdx.x, tid = threadIdx.x, wv = tid >> 6;
    const float4* row4 = w_all4 + (size_t)b * (S_ / 4);

    #pragma unroll
    for (int i = 0; i < 2; i++){
        int j = tid + i * 1024;
        float4 v = row4[j];
        keys[4*j+0] = f2key(v.x); keys[4*j+1] = f2key(v.y);
        keys[4*j+2] = f2key(v.z); keys[4*j+3] = f2key(v.w);
    }
    if (tid == 0){ sprefix = 0u; sremk = K_TOP; }
    __syncthreads();

    for (int pass = 3; pass >= 0; pass--){
        for (int i = tid; i < 16 * 256; i += 1024) ((unsigned*)hist)[i] = 0u;
        __syncthreads();
        const unsigned mask_hi = (pass == 3) ? 0u : (0xFFFFFFFFu << ((pass + 1) * 8));
        const unsigned pfx = sprefix;
        const int shift = pass * 8;
        #pragma unroll
        for (int i = 0; i < 8; i++){
            unsigned key = keys[tid + i * 1024];
            if ((key & mask_hi) == pfx)
                atomicAdd(&hist[wv][(key >> shift) & 255u], 1u);
        }
        __syncthreads();
        if (tid < 256){
            unsigned s = 0;
            #pragma unroll
            for (int h = 0; h < 16; h++) s += hist[h][tid];
            suffix[tid] = s;
        }
        __syncthreads();
        for (int off = 1; off < 256; off <<= 1){
            unsigned v = 0;
            if (tid < 256 && tid + off < 256) v = suffix[tid + off];
            __syncthreads();
            if (tid < 256) suffix[tid] += v;
            __syncthreads();
        }
        const int remk = sremk;
        __syncthreads();
        if (tid < 256){
            unsigned snext = (tid == 255) ? 0u : suffix[tid + 1];
            if (suffix[tid] >= (unsigned)remk && snext < (unsigned)remk){
                sprefix = pfx | ((unsigned)tid << shift);
                sremk = remk - (int)snext;
            }
        }
        __syncthreads();
    }

    const unsigned thr = sprefix;
    #pragma unroll
    for (int i = 0; i < 8; i++){
        int li = tid + i * 1024;
        if (keys[li] > thr){
            int p = atomicAdd(count, 1);
            idx[p] = b * S_ + li;
        }
    }
}

// --- kernel 3: gather selected x rows -> bf16 tiled+swizzled ---------------
// XbT tiles [32 mt][4 ks][128 r][128 k]; grid (32, 4)
__global__ __launch_bounds__(256) void gather_kernel(
    const float* __restrict__ x, const int* __restrict__ idx,
    const int* __restrict__ countp, u16* __restrict__ XbT)
{
    const int mt = blockIdx.x, s = blockIdx.y;
    const int cnt = *countp;
    const int cl = threadIdx.x & 15, r16 = threadIdx.x >> 4;
    u16* base = XbT + (size_t)(mt * 4 + s) * 16384;
    #pragma unroll
    for (int it = 0; it < 8; it++){
        int r = r16 + it * 16;
        int mg = mt * 128 + r;
        if (mg < cnt){
            const float* xp = x + (size_t)idx[mg] * D_ + s * 128 + cl * 8;
            float4 v0 = *(const float4*)xp;
            float4 v1 = *(const float4*)(xp + 4);
            bf16x8 bv;
            bv[0]=(short)f2b(v0.x); bv[1]=(short)f2b(v0.y);
            bv[2]=(short)f2b(v0.z); bv[3]=(short)f2b(v0.w);
            bv[4]=(short)f2b(v1.x); bv[5]=(short)f2b(v1.y);
            bv[6]=(short)f2b(v1.z); bv[7]=(short)f2b(v1.w);
            *(bf16x8*)&base[r * 128 + ((cl ^ (r & 15)) << 3)] = bv;
        }
    }
}

// --- kernel 4: weight fp32 [R=K rows][C=N cols] -> bf16 tiles [C/128][R/128][128 n][128 k]
__global__ __launch_bounds__(256) void tconv_kernel(
    const float* __restrict__ src, u16* __restrict__ dst, int R, int C)
{
    __shared__ float tile[128][129];
    const int ct = blockIdx.x, ks = blockIdx.y;
    const int tid = threadIdx.x;
    #pragma unroll
    for (int it = 0; it < 64; it++){
        int lin = it * 256 + tid;
        int kk = lin >> 7, nn = lin & 127;
        tile[kk][nn] = src[(size_t)(ks * 128 + kk) * C + ct * 128 + nn];
    }
    __syncthreads();
    u16* base = dst + (size_t)(ct * (R / 128) + ks) * 16384;
    const int r = tid >> 1, h = tid & 1;
    #pragma unroll
    for (int c = 0; c < 8; c++){
        int cl = h * 8 + c;
        bf16x8 bv;
        #pragma unroll
        for (int e = 0; e < 8; e++) bv[e] = (short)f2b(tile[cl * 8 + e][r]);
        *(bf16x8*)&base[r * 128 + ((cl ^ (r & 15)) << 3)] = bv;
    }
}

// --- kernel 5: GEMM1  Ht = gelu(Xsel @ W1 + b1), 128x128 tile, BK=128, dbuf
__global__ __launch_bounds__(256) void ffn1_kernel(
    const u16* __restrict__ XbT, const u16* __restrict__ W1t,
    const int* __restrict__ countp, const float* __restrict__ bias1,
    u16* __restrict__ Ht)
{
    __shared__ __align__(16) u16 As[2][16384];
    __shared__ __align__(16) u16 Bs[2][16384];
    const int tid = threadIdx.x;
    const int cnt = *countp;
    const int mBlk = blockIdx.x, nBlk = blockIdx.y;
    const int lane = tid & 63, w = tid >> 6;
    const int wr = (w >> 1) * 64, wc = (w & 1) * 64;
    const int fr = lane & 15, quad = lane >> 4;

    const char* Ag = (const char*)(XbT + (size_t)mBlk * 4 * 16384) + tid * 16;
    const char* Bg = (const char*)(W1t + (size_t)nBlk * 4 * 16384) + tid * 16;

    #pragma unroll
    for (int i = 0; i < 8; i++){
        gl_lds16(Ag + i*4096, (char*)As[0] + tid*16 + i*4096);
        gl_lds16(Bg + i*4096, (char*)Bs[0] + tid*16 + i*4096);
    }

    floatx4 acc[4][4] = {};
    for (int ksi = 0; ksi < 4; ksi++){
        __syncthreads();
        if (ksi + 1 < 4){
            const char* An = Ag + (size_t)(ksi+1) * 32768;
            const char* Bn = Bg + (size_t)(ksi+1) * 32768;
            char* Al = (char*)As[(ksi+1)&1] + tid*16;
            char* Bl = (char*)Bs[(ksi+1)&1] + tid*16;
            #pragma unroll
            for (int i = 0; i < 8; i++){
                gl_lds16(An + i*4096, Al + i*4096);
                gl_lds16(Bn + i*4096, Bl + i*4096);
            }
        }
        const u16* Ab = As[ksi&1];
        const u16* Bb = Bs[ksi&1];
        #pragma unroll
        for (int ks2 = 0; ks2 < 4; ks2++){
            bf16x8 af[4], bf[4];
            #pragma unroll
            for (int i = 0; i < 4; i++){
                int r = wr + i*16 + fr;
                af[i] = *(const bf16x8*)&Ab[r*128 + (((ks2*4 + quad) ^ (r & 15)) << 3)];
            }
            #pragma unroll
            for (int j = 0; j < 4; j++){
                int r = wc + j*16 + fr;
                bf[j] = *(const bf16x8*)&Bb[r*128 + (((ks2*4 + quad) ^ (r & 15)) << 3)];
            }
            #pragma unroll
            for (int i = 0; i < 4; i++)
                #pragma unroll
                for (int j = 0; j < 4; j++)
                    acc[i][j] = __builtin_amdgcn_mfma_f32_16x16x32_bf16(af[i], bf[j], acc[i][j], 0, 0, 0);
        }
    }

    float bj[4];
    #pragma unroll
    for (int j = 0; j < 4; j++) bj[j] = bias1[nBlk*128 + wc + j*16 + fr];

    // stage C tile (post-gelu bf16) in LDS, then coalesced copy-out to Ht
    __syncthreads();
    u16* Cs = (u16*)As;              // 32KB: [128 r][128 c] swizzled
    #pragma unroll
    for (int i = 0; i < 4; i++){
        #pragma unroll
        for (int rg = 0; rg < 4; rg++){
            int r = wr + i*16 + quad*4 + rg;
            #pragma unroll
            for (int j = 0; j < 4; j++){
                int col = wc + j*16 + fr;
                float v = gelu_fast(acc[i][j][rg] + bj[j]);
                Cs[r*128 + ((((col >> 3) ^ (r & 15)) << 3) | (col & 7))] = f2b(v);
            }
        }
    }
    __syncthreads();
    const int r = tid >> 1, h = tid & 1;
    int mg = mBlk*128 + r;
    if (mg < cnt){
        // Ht subtile (mt64 = mBlk*2 + (r>>6), ks = nBlk), rows [64][128]
        u16* dstp = Ht + (((size_t)(mBlk*2 + (r >> 6)) * 16 + nBlk) * 64 + (r & 63)) * 128;
        #pragma unroll
        for (int p = 0; p < 8; p++){
            int pc = h*8 + p;
            *(bf16x8*)&dstp[pc << 3] = *(const bf16x8*)&Cs[r*128 + (pc << 3)];
        }
    }
}

// --- kernel 6: GEMM2  out[token] = (H @ W2 + b2) * w, 64x128 tile, BK=128 --
__global__ __launch_bounds__(256) void ffn2_kernel(
    const u16* __restrict__ Ht, const u16* __restrict__ W2t,
    const int* __restrict__ countp, const int* __restrict__ idx,
    const float* __restrict__ w_all, const float* __restrict__ bias2,
    float* __restrict__ out)
{
    __shared__ __align__(16) u16 As[2][8192];    // [64][128]
    __shared__ __align__(16) u16 Bs[2][16384];   // [128][128]
    const int tid = threadIdx.x;
    const int cnt = *countp;
    const int mBlk = blockIdx.x, nBlk = blockIdx.y;
    const int lane = tid & 63, w = tid >> 6;
    const int wr = (w >> 1) * 32, wc = (w & 1) * 64;
    const int fr = lane & 15, quad = lane >> 4;

    const char* Ag = (const char*)(Ht + (size_t)mBlk * 16 * 8192) + tid * 16;
    const char* Bg = (const char*)(W2t + (size_t)nBlk * 16 * 16384) + tid * 16;

    #pragma unroll
    for (int i = 0; i < 4; i++) gl_lds16(Ag + i*4096, (char*)As[0] + tid*16 + i*4096);
    #pragma unroll
    for (int i = 0; i < 8; i++) gl_lds16(Bg + i*4096, (char*)Bs[0] + tid*16 + i*4096);

    floatx4 acc[2][4] = {};
    for (int ksi = 0; ksi < 16; ksi++){
        __syncthreads();
        if (ksi + 1 < 16){
            const char* An = Ag + (size_t)(ksi+1) * 16384;
            const char* Bn = Bg + (size_t)(ksi+1) * 32768;
            char* Al = (char*)As[(ksi+1)&1] + tid*16;
            char* Bl = (char*)Bs[(ksi+1)&1] + tid*16;
            #pragma unroll
            for (int i = 0; i < 4; i++) gl_lds16(An + i*4096, Al + i*4096);
            #pragma unroll
            for (int i = 0; i < 8; i++) gl_lds16(Bn + i*4096, Bl + i*4096);
        }
        const u16* Ab = As[ksi&1];
        const u16* Bb = Bs[ksi&1];
        #pragma unroll
        for (int ks2 = 0; ks2 < 4; ks2++){
            bf16x8 af[2], bf[4];
            #pragma unroll
            for (int i = 0; i < 2; i++){
                int r = wr + i*16 + fr;
                af[i] = *(const bf16x8*)&Ab[r*128 + (((ks2*4 + quad) ^ (r & 15)) << 3)];
            }
            #pragma unroll
            for (int j = 0; j < 4; j++){
                int r = wc + j*16 + fr;
                bf[j] = *(const bf16x8*)&Bb[r*128 + (((ks2*4 + quad) ^ (r & 15)) << 3)];
            }
            #pragma unroll
            for (int i = 0; i < 2; i++)
                #pragma unroll
                for (int j = 0; j < 4; j++)
                    acc[i][j] = __builtin_amdgcn_mfma_f32_16x16x32_bf16(af[i], bf[j], acc[i][j], 0, 0, 0);
        }
    }

    float bj[4];
    #pragma unroll
    for (int j = 0; j < 4; j++) bj[j] = bias2[nBlk*128 + wc + j*16 + fr];

    // stage C (acc + bias) as f32 in LDS, then per-row coalesced scatter * wt
    __syncthreads();
    float* Cs = (float*)Bs;          // 32KB: [64 r][128 c]
    #pragma unroll
    for (int i = 0; i < 2; i++){
        #pragma unroll
        for (int rg = 0; rg < 4; rg++){
            int r = wr + i*16 + quad*4 + rg;
            #pragma unroll
            for (int j = 0; j < 4; j++)
                Cs[r*128 + wc + j*16 + fr] = acc[i][j][rg] + bj[j];
        }
    }
    __syncthreads();
    const int r = tid >> 2, q = tid & 3;
    int mg = mBlk*64 + r;
    if (mg < cnt){
        int token = idx[mg];
        float wt = w_all[token];
        float* op = out + (size_t)token * D_ + nBlk*128 + q*32;
        const float4* cp = (const float4*)&Cs[r*128 + q*32];
        #pragma unroll
        for (int p = 0; p < 8; p++){
            float4 vv = cp[p];
            vv.x *= wt; vv.y *= wt; vv.z *= wt; vv.w *= wt;
            ((float4*)op)[p] = vv;
        }
    }
}

extern "C" void kernel_launch(void* const* d_in, const int* in_sizes, int n_in,
                              void* d_out, int out_size, void* d_ws, size_t ws_size,
                              hipStream_t stream)
{
    const float* x  = (const float*)d_in[0];
    const float* Wr = (const float*)d_in[2];
    const float* br = (const float*)d_in[3];
    const float* W1 = (const float*)d_in[4];
    const float* b1 = (const float*)d_in[5];
    const float* W2 = (const float*)d_in[6];
    const float* b2 = (const float*)d_in[7];
    float* out = (float*)d_out;
    char* ws = (char*)d_ws;

    // workspace layout (bytes)
    float* w_all = (float*)(ws + 0);          // 128 KB
    int*   count = (int*)  (ws + 131088);
    int*   idx   = (int*)  (ws + 131104);     // 4096 ints
    u16*   XbT   = (u16*)  (ws + 262144);     // 4 MB  [32][4][128][128]
    u16*   W1t   = (u16*)  (ws + 4456448);    // 2 MB  [16][4][128][128]
    u16*   W2t   = (u16*)  (ws + 6553600);    // 2 MB  [4][16][128][128]
    u16*   Ht    = (u16*)  (ws + 8650752);    // 16 MB [64][16][64][128]

    tconv_kernel<<<dim3(DFF_/128, D_/128),  256, 0, stream>>>(W1, W1t, D_, DFF_);
    tconv_kernel<<<dim3(D_/128,  DFF_/128), 256, 0, stream>>>(W2, W2t, DFF_, D_);
    wts_copy_kernel<<<(B_*S_)/4, 256, 0, stream>>>(
        (const float4*)x, (float4*)out, (const float4*)Wr, br, w_all, count);
    kth_compact_kernel<<<B_, 1024, 0, stream>>>((const float4*)w_all, count, idx);
    gather_kernel<<<dim3(32, 4), 256, 0, stream>>>(x, idx, count, XbT);
    ffn1_kernel<<<dim3(32, DFF_/128), 256, 0, stream>>>(XbT, W1t, count, b1, Ht);
    ffn2_kernel<<<dim3(64, D_/128),   256, 0, stream>>>(Ht, W2t, count, idx, w_all, b2, out);
}